// Round 10
// baseline (249.690 us; speedup 1.0000x reference)
//
#include <hip/hip_runtime.h>

#define HH 128
#define GG 32
#define LL 3
#define BN_EPS 1e-5f

typedef unsigned short ushortT;
typedef unsigned int uintT;
typedef __attribute__((ext_vector_type(8))) short bf16x8;
typedef __attribute__((ext_vector_type(4))) float f32x4;

__device__ inline ushortT f2bf(float f) {
  uintT u = __float_as_uint(f);
  u += 0x7fff + ((u >> 16) & 1);  // RNE
  return (ushortT)(u >> 16);
}
__device__ inline float bf2f(ushortT u) { return __uint_as_float(((uintT)u) << 16); }

// ---- XCD-windowed degree count: window w = blockIdx%8 -> one XCD owns deg[lo,hi) ----
__global__ __launch_bounds__(256) void k_degw(const int* __restrict__ ei, int* __restrict__ deg,
                                              int E, int win) {
  int w = blockIdx.x & 7;
  int lo = w * win, hi = lo + win;
  int idx = (blockIdx.x >> 3) * 256 + threadIdx.x;
  int stride = (gridDim.x >> 3) * 256;
  for (int e = idx; e < E; e += stride) {
    int d = ei[E + e];
    if (d >= lo && d < hi) atomicAdd(&deg[d], 1);
  }
}

// ---- XCD-windowed scatter: cursor atomics + csr writes stay in one XCD's L2 ----
__global__ __launch_bounds__(256) void k_scatw(const int* __restrict__ ei, int* __restrict__ cursor,
                                               ushortT* __restrict__ csr_us, int E, int win) {
  int w = blockIdx.x & 7;
  int lo = w * win, hi = lo + win;
  int idx = (blockIdx.x >> 3) * 256 + threadIdx.x;
  int stride = (gridDim.x >> 3) * 256;
  for (int e = idx; e < E; e += stride) {
    int d = ei[E + e];
    if (d >= lo && d < hi) {
      int pos = atomicAdd(&cursor[d], 1);
      csr_us[pos] = (ushortT)ei[e];
    }
  }
}

// ---- cast fp32 rows -> bf16 mirror ----
__global__ __launch_bounds__(256) void k_cast(const float* __restrict__ in, ushortT* __restrict__ outb, int total4) {
  int i = blockIdx.x * 256 + threadIdx.x;
  if (i < total4) {
    float4 v = *(const float4*)&in[(size_t)i * 4];
    ushort4 o;
    o.x = f2bf(v.x); o.y = f2bf(v.y); o.z = f2bf(v.z); o.w = f2bf(v.w);
    *(ushort4*)&outb[(size_t)i * 4] = o;
  }
}

// ---- graph boundaries via binary search (batch is sorted); goff[B] = N sentinel ----
__global__ __launch_bounds__(256) void k_gbounds(const int* __restrict__ batch, int* __restrict__ goff,
                                                 int N, int B) {
  int g = blockIdx.x * 256 + threadIdx.x;
  if (g > B) return;
  if (g == B) { goff[B] = N; return; }
  int lo = 0, hi = N;
  while (lo < hi) {
    int mid = (lo + hi) >> 1;
    if (batch[mid] < g) lo = mid + 1; else hi = mid;
  }
  goff[g] = lo;
}

// ---- scan: block-local phase ----
__global__ __launch_bounds__(1024) void k_scan_blk(const int* __restrict__ in, int* __restrict__ out,
                                                   int* __restrict__ bsum, int n) {
  __shared__ int sd[1024];
  int tid = threadIdx.x;
  int i = blockIdx.x * 1024 + tid;
  int v = (i < n) ? in[i] : 0;
  sd[tid] = v;
  __syncthreads();
  for (int off = 1; off < 1024; off <<= 1) {
    int t = (tid >= off) ? sd[tid - off] : 0;
    __syncthreads();
    sd[tid] += t;
    __syncthreads();
  }
  if (i < n) out[i] = sd[tid] - v;
  if (tid == 1023) bsum[blockIdx.x] = sd[1023];
}

__global__ __launch_bounds__(1024) void k_scan_top(int* __restrict__ bsum, int nb) {
  __shared__ int sd[1024];
  int tid = threadIdx.x;
  int v = (tid < nb) ? bsum[tid] : 0;
  sd[tid] = v;
  __syncthreads();
  for (int off = 1; off < 1024; off <<= 1) {
    int t = (tid >= off) ? sd[tid - off] : 0;
    __syncthreads();
    sd[tid] += t;
    __syncthreads();
  }
  if (tid < nb) bsum[tid] = sd[tid] - v;
}

__global__ __launch_bounds__(1024) void k_scan_add(int* __restrict__ out0, int* __restrict__ out1,
                                                   const int* __restrict__ bsum, int n) {
  int i = blockIdx.x * 1024 + threadIdx.x;
  if (i < n) {
    int v = out0[i] + bsum[blockIdx.x];
    out0[i] = v;
    out1[i] = v;  // cursor copy for windowed scatter
  }
}

// ---- pack weights for MFMA B-fragment reads ----
__global__ __launch_bounds__(256) void k_prepw(const float* __restrict__ wl, const float* __restrict__ wr,
                                               ushortT* __restrict__ wpack) {
  int idx = blockIdx.x * 256 + threadIdx.x;
  if (idx >= LL * 8 * 128 * 4) return;
  int q = idx & 3;
  int n = (idx >> 2) & 127;
  int kf = (idx >> 9) & 7;
  int layer = idx >> 12;
  ushortT tmp[8];
#pragma unroll
  for (int j = 0; j < 8; j++) {
    int k = kf * 32 + q * 8 + j;
    float w = (k < HH) ? wl[(size_t)layer * HH * HH + k * HH + n]
                       : wr[(size_t)layer * HH * HH + (k - HH) * HH + n];
    tmp[j] = f2bf(w);
  }
  ushort4 a = {tmp[0], tmp[1], tmp[2], tmp[3]};
  ushort4 b = {tmp[4], tmp[5], tmp[6], tmp[7]};
  *(ushort4*)&wpack[(size_t)idx * 8] = a;
  *(ushort4*)&wpack[(size_t)idx * 8 + 4] = b;
}

// ---- mean aggregation: one wave per node, full 256B-row bf16 gather, 8 rows in flight ----
__global__ __launch_bounds__(256) void k_aggregate(const int* __restrict__ csr_off, const int* __restrict__ deg,
                                                   const ushortT* __restrict__ csr_us, const ushortT* __restrict__ hinb,
                                                   ushortT* __restrict__ aggb, int N) {
  int wid = (blockIdx.x * 256 + threadIdx.x) >> 6;
  int lane = threadIdx.x & 63;
  if (wid >= N) return;
  int off = csr_off[wid];
  int d = deg[wid];
  int half = lane >> 5;
  int colq = (lane & 31) * 4;
  float ax = 0.f, ay = 0.f, az = 0.f, aw = 0.f;
  int j = 0;
  for (; j + 8 <= d; j += 8) {  // 8 rows (2KB) in flight
    int s0 = csr_us[off + j + half];
    int s1 = csr_us[off + j + 2 + half];
    int s2 = csr_us[off + j + 4 + half];
    int s3 = csr_us[off + j + 6 + half];
    ushort4 v0 = *(const ushort4*)&hinb[(size_t)s0 * HH + colq];
    ushort4 v1 = *(const ushort4*)&hinb[(size_t)s1 * HH + colq];
    ushort4 v2 = *(const ushort4*)&hinb[(size_t)s2 * HH + colq];
    ushort4 v3 = *(const ushort4*)&hinb[(size_t)s3 * HH + colq];
    ax += bf2f(v0.x); ay += bf2f(v0.y); az += bf2f(v0.z); aw += bf2f(v0.w);
    ax += bf2f(v1.x); ay += bf2f(v1.y); az += bf2f(v1.z); aw += bf2f(v1.w);
    ax += bf2f(v2.x); ay += bf2f(v2.y); az += bf2f(v2.z); aw += bf2f(v2.w);
    ax += bf2f(v3.x); ay += bf2f(v3.y); az += bf2f(v3.z); aw += bf2f(v3.w);
  }
  for (; j + 2 <= d; j += 2) {
    int s = csr_us[off + j + half];
    ushort4 v = *(const ushort4*)&hinb[(size_t)s * HH + colq];
    ax += bf2f(v.x); ay += bf2f(v.y); az += bf2f(v.z); aw += bf2f(v.w);
  }
  if (j < d && half == 0) {
    int s = csr_us[off + j];
    ushort4 v = *(const ushort4*)&hinb[(size_t)s * HH + colq];
    ax += bf2f(v.x); ay += bf2f(v.y); az += bf2f(v.z); aw += bf2f(v.w);
  }
  ax += __shfl_down(ax, 32);
  ay += __shfl_down(ay, 32);
  az += __shfl_down(az, 32);
  aw += __shfl_down(aw, 32);
  if (half == 0) {
    float inv = d > 0 ? 1.0f / (float)d : 0.0f;
    ushort4 o;
    o.x = f2bf(ax * inv); o.y = f2bf(ay * inv); o.z = f2bf(az * inv); o.w = f2bf(aw * inv);
    *(ushort4*)&aggb[(size_t)wid * HH + colq] = o;
  }
}

// ---- MFMA dual GEMM + bias + BN + ReLU -> bf16 h ----
__global__ __launch_bounds__(256) void k_gemm(const ushortT* __restrict__ aggb, const ushortT* __restrict__ hinb,
                                              const ushortT* __restrict__ wpack, const float* __restrict__ bias,
                                              const float* __restrict__ gma, const float* __restrict__ bta,
                                              const float* __restrict__ mea, const float* __restrict__ var,
                                              ushortT* __restrict__ houtb, int N) {
  __shared__ char Asm[64 * 512];  // 64 rows x 256 bf16, XOR-swizzled
  int tid = threadIdx.x;
  int l = tid & 63;
  int w = tid >> 6;
  int n0 = blockIdx.x * 64;
  int q = l >> 4;
  int ln = l & 15;

  bf16x8 bfr[8][2];
#pragma unroll
  for (int kf = 0; kf < 8; kf++)
#pragma unroll
    for (int nf = 0; nf < 2; nf++) {
      size_t off = (((size_t)kf * 128 + (w * 32 + nf * 16 + ln)) * 4 + q) * 8;
      bfr[kf][nf] = *(const bf16x8*)(wpack + off);
    }

#pragma unroll
  for (int r2 = 0; r2 < 8; r2++) {
    int c = r2 * 256 + tid;
    int row = c >> 5;
    int col16 = c & 31;
    int rg = n0 + row;
    rg = rg < N ? rg : N - 1;
    const ushortT* src = (col16 < 16) ? (aggb + (size_t)rg * HH + col16 * 8)
                                      : (hinb + (size_t)rg * HH + (col16 - 16) * 8);
    float4 v = *(const float4*)src;
    int waddr = row * 512 + ((col16 * 16) ^ ((row & 7) << 4));
    *(float4*)(Asm + waddr) = v;
  }
  __syncthreads();

  f32x4 acc[4][2] = {};
#pragma unroll
  for (int kf = 0; kf < 8; kf++) {
#pragma unroll
    for (int rt = 0; rt < 4; rt++) {
      int row = rt * 16 + ln;
      int raddr = row * 512 + ((kf * 64 + q * 16) ^ ((row & 7) << 4));
      bf16x8 a = *(const bf16x8*)(Asm + raddr);
      acc[rt][0] = __builtin_amdgcn_mfma_f32_16x16x32_bf16(a, bfr[kf][0], acc[rt][0], 0, 0, 0);
      acc[rt][1] = __builtin_amdgcn_mfma_f32_16x16x32_bf16(a, bfr[kf][1], acc[rt][1], 0, 0, 0);
    }
  }

  float sc[2], sh[2];
  int colg[2];
#pragma unroll
  for (int nf = 0; nf < 2; nf++) {
    int c = w * 32 + nf * 16 + ln;
    colg[nf] = c;
    float g = gma[c], vv = var[c], m = mea[c], bt = bta[c], bb = bias[c];
    float s = g * rsqrtf(vv + BN_EPS);
    sc[nf] = s;
    sh[nf] = (bb - m) * s + bt;
  }
#pragma unroll
  for (int rt = 0; rt < 4; rt++)
#pragma unroll
    for (int j = 0; j < 4; j++) {
      int row = n0 + rt * 16 + q * 4 + j;
      if (row < N) {
#pragma unroll
        for (int nf = 0; nf < 2; nf++) {
          float v = fmaxf(acc[rt][nf][j] * sc[nf] + sh[nf], 0.f);
          houtb[(size_t)row * HH + colg[nf]] = f2bf(v);
        }
      }
    }
}

// ---- fused pooling + MLP: one block (128 thr) per graph ----
__global__ __launch_bounds__(128) void k_poolmlp(const ushortT* __restrict__ hb, const int* __restrict__ goff,
                                                 const float* __restrict__ gfeat,
                                                 const float* __restrict__ w1, const float* __restrict__ b1,
                                                 const float* __restrict__ w2, const float* __restrict__ b2,
                                                 float* __restrict__ out) {
  __shared__ float z[HH + GG];
  int g = blockIdx.x;
  int t = threadIdx.x;
  int off = goff[g];
  int cnt = goff[g + 1] - off;
  float s = 0.f;
  int j = 0;
  for (; j + 2 <= cnt; j += 2)
    s += bf2f(hb[(size_t)(off + j) * HH + t]) + bf2f(hb[(size_t)(off + j + 1) * HH + t]);
  if (j < cnt) s += bf2f(hb[(size_t)(off + j) * HH + t]);
  z[t] = s * (cnt > 0 ? 1.0f / (float)cnt : 0.f);
  if (t < GG) z[HH + t] = gfeat[g * GG + t];
  __syncthreads();
  if (t < 64) {
    float acc = b1[t];
#pragma unroll 8
    for (int k = 0; k < HH + GG; k++) acc = fmaf(z[k], w1[k * 64 + t], acc);
    acc = fmaxf(acc, 0.f) * w2[t];
#pragma unroll
    for (int o = 32; o > 0; o >>= 1) acc += __shfl_down(acc, o);
    if (t == 0) out[g] = acc + b2[0];
  }
}

extern "C" void kernel_launch(void* const* d_in, const int* in_sizes, int n_in,
                              void* d_out, int out_size, void* d_ws, size_t ws_size,
                              hipStream_t stream) {
  const float* x = (const float*)d_in[0];
  const int* ei = (const int*)d_in[1];
  const int* batch = (const int*)d_in[2];
  const float* gfeat = (const float*)d_in[3];
  const float* wl = (const float*)d_in[4];
  const float* wr = (const float*)d_in[5];
  const float* bias = (const float*)d_in[6];
  const float* gma = (const float*)d_in[7];
  const float* bta = (const float*)d_in[8];
  const float* mea = (const float*)d_in[9];
  const float* var = (const float*)d_in[10];
  const float* w1 = (const float*)d_in[11];
  const float* b1 = (const float*)d_in[12];
  const float* w2 = (const float*)d_in[13];
  const float* b2 = (const float*)d_in[14];
  int N = in_sizes[0] / HH;
  int E = in_sizes[1] / 2;
  int B = in_sizes[3] / GG;
  float* out = (float*)d_out;
  (void)n_in; (void)out_size; (void)ws_size;

  char* base = (char*)d_ws;
  size_t off = 0;
  auto alloc = [&](size_t bytes) -> void* {
    void* p = base + off;
    off = (off + bytes + 255) & ~(size_t)255;
    return p;
  };
  int* deg = (int*)alloc((size_t)N * 4);
  int* csr_off = (int*)alloc((size_t)N * 4);
  int* cursor = (int*)alloc((size_t)N * 4);
  int* goff = (int*)alloc((size_t)(B + 1) * 4);
  ushortT* csr_us = (ushortT*)alloc((size_t)E * 2);
  ushortT* xb = (ushortT*)alloc((size_t)N * HH * 2);
  ushortT* h1b = (ushortT*)alloc((size_t)N * HH * 2);
  ushortT* h2b = (ushortT*)alloc((size_t)N * HH * 2);
  ushortT* aggb = (ushortT*)alloc((size_t)N * HH * 2);
  ushortT* wpack = (ushortT*)alloc((size_t)LL * 8 * 128 * 4 * 8 * 2);
  int* bsumN = (int*)alloc(1024 * 4);

  hipMemsetAsync(deg, 0, (size_t)N * 4, stream);

  int win = (N + 7) / 8;
  k_degw<<<2048, 256, 0, stream>>>(ei, deg, E, win);
  int total4 = N * HH / 4;
  k_cast<<<(total4 + 255) / 256, 256, 0, stream>>>(x, xb, total4);
  k_gbounds<<<(B + 256) / 256, 256, 0, stream>>>(batch, goff, N, B);

  int nbN = (N + 1023) / 1024;
  k_scan_blk<<<nbN, 1024, 0, stream>>>(deg, csr_off, bsumN, N);
  k_scan_top<<<1, 1024, 0, stream>>>(bsumN, nbN);
  k_scan_add<<<nbN, 1024, 0, stream>>>(csr_off, cursor, bsumN, N);

  k_scatw<<<2048, 256, 0, stream>>>(ei, cursor, csr_us, E, win);

  k_prepw<<<(LL * 8 * 128 * 4 + 255) / 256, 256, 0, stream>>>(wl, wr, wpack);

  int nblk = (N + 63) / 64;
  int agg_blk = (N + 3) / 4;  // one wave per node, 4 waves/block
  const ushortT* hsrc[LL] = {xb, h1b, h2b};
  ushortT* hdst[LL] = {h1b, h2b, h1b};
  for (int lyr = 0; lyr < LL; lyr++) {
    k_aggregate<<<agg_blk, 256, 0, stream>>>(csr_off, deg, csr_us, hsrc[lyr], aggb, N);
    k_gemm<<<nblk, 256, 0, stream>>>(aggb, hsrc[lyr], wpack + (size_t)lyr * 32768,
                                     bias + (size_t)lyr * HH, gma + (size_t)lyr * HH, bta + (size_t)lyr * HH,
                                     mea + (size_t)lyr * HH, var + (size_t)lyr * HH, hdst[lyr], N);
  }
  k_poolmlp<<<B, 128, 0, stream>>>(h1b, goff, gfeat, w1, b1, w2, b2, out);
}

// Round 11
// 239.111 us; speedup vs baseline: 1.0442x; 1.0442x over previous
//
#include <hip/hip_runtime.h>

#define HH 128
#define GG 32
#define LL 3
#define BN_EPS 1e-5f

typedef unsigned short ushortT;
typedef unsigned int uintT;
typedef __attribute__((ext_vector_type(8))) short bf16x8;
typedef __attribute__((ext_vector_type(4))) float f32x4;

__device__ inline ushortT f2bf(float f) {
  uintT u = __float_as_uint(f);
  u += 0x7fff + ((u >> 16) & 1);  // RNE
  return (ushortT)(u >> 16);
}
__device__ inline float bf2f(ushortT u) { return __uint_as_float(((uintT)u) << 16); }

// ---- degree count + edge packing + per-edge rank (atomic returns rank within dst list) ----
__global__ __launch_bounds__(256) void k_degpack(const int* __restrict__ ei, int* __restrict__ deg,
                                                 uintT* __restrict__ packed, ushortT* __restrict__ rank, int E) {
  int e = blockIdx.x * 256 + threadIdx.x;
  if (e < E) {
    int d = ei[E + e];
    int s = ei[e];
    int r = atomicAdd(&deg[d], 1);
    __builtin_nontemporal_store(((uintT)d << 16) | (uintT)s, &packed[e]);
    __builtin_nontemporal_store((ushortT)r, &rank[e]);
  }
}

// ---- cast fp32 rows -> bf16 mirror ----
__global__ __launch_bounds__(256) void k_cast(const float* __restrict__ in, ushortT* __restrict__ outb, int total4) {
  int i = blockIdx.x * 256 + threadIdx.x;
  if (i < total4) {
    float4 v = *(const float4*)&in[(size_t)i * 4];
    ushort4 o;
    o.x = f2bf(v.x); o.y = f2bf(v.y); o.z = f2bf(v.z); o.w = f2bf(v.w);
    *(ushort4*)&outb[(size_t)i * 4] = o;
  }
}

// ---- graph boundaries via binary search (batch is sorted); goff[B] = N sentinel ----
__global__ __launch_bounds__(256) void k_gbounds(const int* __restrict__ batch, int* __restrict__ goff,
                                                 int N, int B) {
  int g = blockIdx.x * 256 + threadIdx.x;
  if (g > B) return;
  if (g == B) { goff[B] = N; return; }
  int lo = 0, hi = N;
  while (lo < hi) {
    int mid = (lo + hi) >> 1;
    if (batch[mid] < g) lo = mid + 1; else hi = mid;
  }
  goff[g] = lo;
}

// ---- scan: block-local phase ----
__global__ __launch_bounds__(1024) void k_scan_blk(const int* __restrict__ in, int* __restrict__ out,
                                                   int* __restrict__ bsum, int n) {
  __shared__ int sd[1024];
  int tid = threadIdx.x;
  int i = blockIdx.x * 1024 + tid;
  int v = (i < n) ? in[i] : 0;
  sd[tid] = v;
  __syncthreads();
  for (int off = 1; off < 1024; off <<= 1) {
    int t = (tid >= off) ? sd[tid - off] : 0;
    __syncthreads();
    sd[tid] += t;
    __syncthreads();
  }
  if (i < n) out[i] = sd[tid] - v;
  if (tid == 1023) bsum[blockIdx.x] = sd[1023];
}

__global__ __launch_bounds__(1024) void k_scan_top(int* __restrict__ bsum, int nb) {
  __shared__ int sd[1024];
  int tid = threadIdx.x;
  int v = (tid < nb) ? bsum[tid] : 0;
  sd[tid] = v;
  __syncthreads();
  for (int off = 1; off < 1024; off <<= 1) {
    int t = (tid >= off) ? sd[tid - off] : 0;
    __syncthreads();
    sd[tid] += t;
    __syncthreads();
  }
  if (tid < nb) bsum[tid] = sd[tid] - v;
}

__global__ __launch_bounds__(1024) void k_scan_add(int* __restrict__ out0, const int* __restrict__ bsum, int n) {
  int i = blockIdx.x * 1024 + threadIdx.x;
  if (i < n) out0[i] += bsum[blockIdx.x];
}

// ---- atomic-free scatter: pos = csr_off[d] + rank[e] ----
__global__ __launch_bounds__(256) void k_scatter(const uintT* __restrict__ packed, const ushortT* __restrict__ rank,
                                                 const int* __restrict__ csr_off, ushortT* __restrict__ csr_us, int E) {
  int e = blockIdx.x * 256 + threadIdx.x;
  if (e < E) {
    uintT p = packed[e];
    int d = (int)(p >> 16);
    int pos = csr_off[d] + (int)rank[e];
    __builtin_nontemporal_store((ushortT)(p & 0xffffu), &csr_us[pos]);
  }
}

// ---- pack weights for MFMA B-fragment reads ----
__global__ __launch_bounds__(256) void k_prepw(const float* __restrict__ wl, const float* __restrict__ wr,
                                               ushortT* __restrict__ wpack) {
  int idx = blockIdx.x * 256 + threadIdx.x;
  if (idx >= LL * 8 * 128 * 4) return;
  int q = idx & 3;
  int n = (idx >> 2) & 127;
  int kf = (idx >> 9) & 7;
  int layer = idx >> 12;
  ushortT tmp[8];
#pragma unroll
  for (int j = 0; j < 8; j++) {
    int k = kf * 32 + q * 8 + j;
    float w = (k < HH) ? wl[(size_t)layer * HH * HH + k * HH + n]
                       : wr[(size_t)layer * HH * HH + (k - HH) * HH + n];
    tmp[j] = f2bf(w);
  }
  ushort4 a = {tmp[0], tmp[1], tmp[2], tmp[3]};
  ushort4 b = {tmp[4], tmp[5], tmp[6], tmp[7]};
  *(ushort4*)&wpack[(size_t)idx * 8] = a;
  *(ushort4*)&wpack[(size_t)idx * 8 + 4] = b;
}

// ---- mean aggregation: one wave per node, full 256B-row bf16 gather, 16 rows in flight ----
__global__ __launch_bounds__(256) void k_aggregate(const int* __restrict__ csr_off, const int* __restrict__ deg,
                                                   const ushortT* __restrict__ csr_us, const ushortT* __restrict__ hinb,
                                                   ushortT* __restrict__ aggb, int N) {
  int wid = (blockIdx.x * 256 + threadIdx.x) >> 6;
  int lane = threadIdx.x & 63;
  if (wid >= N) return;
  int off = csr_off[wid];
  int d = deg[wid];
  int half = lane >> 5;
  int colq = (lane & 31) * 4;
  float ax = 0.f, ay = 0.f, az = 0.f, aw = 0.f;
  int j = 0;
  for (; j + 16 <= d; j += 16) {  // 16 rows (4KB) in flight
    int s0 = csr_us[off + j + half];
    int s1 = csr_us[off + j + 2 + half];
    int s2 = csr_us[off + j + 4 + half];
    int s3 = csr_us[off + j + 6 + half];
    int s4 = csr_us[off + j + 8 + half];
    int s5 = csr_us[off + j + 10 + half];
    int s6 = csr_us[off + j + 12 + half];
    int s7 = csr_us[off + j + 14 + half];
    ushort4 v0 = *(const ushort4*)&hinb[(size_t)s0 * HH + colq];
    ushort4 v1 = *(const ushort4*)&hinb[(size_t)s1 * HH + colq];
    ushort4 v2 = *(const ushort4*)&hinb[(size_t)s2 * HH + colq];
    ushort4 v3 = *(const ushort4*)&hinb[(size_t)s3 * HH + colq];
    ushort4 v4 = *(const ushort4*)&hinb[(size_t)s4 * HH + colq];
    ushort4 v5 = *(const ushort4*)&hinb[(size_t)s5 * HH + colq];
    ushort4 v6 = *(const ushort4*)&hinb[(size_t)s6 * HH + colq];
    ushort4 v7 = *(const ushort4*)&hinb[(size_t)s7 * HH + colq];
    ax += bf2f(v0.x); ay += bf2f(v0.y); az += bf2f(v0.z); aw += bf2f(v0.w);
    ax += bf2f(v1.x); ay += bf2f(v1.y); az += bf2f(v1.z); aw += bf2f(v1.w);
    ax += bf2f(v2.x); ay += bf2f(v2.y); az += bf2f(v2.z); aw += bf2f(v2.w);
    ax += bf2f(v3.x); ay += bf2f(v3.y); az += bf2f(v3.z); aw += bf2f(v3.w);
    ax += bf2f(v4.x); ay += bf2f(v4.y); az += bf2f(v4.z); aw += bf2f(v4.w);
    ax += bf2f(v5.x); ay += bf2f(v5.y); az += bf2f(v5.z); aw += bf2f(v5.w);
    ax += bf2f(v6.x); ay += bf2f(v6.y); az += bf2f(v6.z); aw += bf2f(v6.w);
    ax += bf2f(v7.x); ay += bf2f(v7.y); az += bf2f(v7.z); aw += bf2f(v7.w);
  }
  for (; j + 8 <= d; j += 8) {  // 8 rows (2KB) in flight
    int s0 = csr_us[off + j + half];
    int s1 = csr_us[off + j + 2 + half];
    int s2 = csr_us[off + j + 4 + half];
    int s3 = csr_us[off + j + 6 + half];
    ushort4 v0 = *(const ushort4*)&hinb[(size_t)s0 * HH + colq];
    ushort4 v1 = *(const ushort4*)&hinb[(size_t)s1 * HH + colq];
    ushort4 v2 = *(const ushort4*)&hinb[(size_t)s2 * HH + colq];
    ushort4 v3 = *(const ushort4*)&hinb[(size_t)s3 * HH + colq];
    ax += bf2f(v0.x); ay += bf2f(v0.y); az += bf2f(v0.z); aw += bf2f(v0.w);
    ax += bf2f(v1.x); ay += bf2f(v1.y); az += bf2f(v1.z); aw += bf2f(v1.w);
    ax += bf2f(v2.x); ay += bf2f(v2.y); az += bf2f(v2.z); aw += bf2f(v2.w);
    ax += bf2f(v3.x); ay += bf2f(v3.y); az += bf2f(v3.z); aw += bf2f(v3.w);
  }
  for (; j + 2 <= d; j += 2) {
    int s = csr_us[off + j + half];
    ushort4 v = *(const ushort4*)&hinb[(size_t)s * HH + colq];
    ax += bf2f(v.x); ay += bf2f(v.y); az += bf2f(v.z); aw += bf2f(v.w);
  }
  if (j < d && half == 0) {
    int s = csr_us[off + j];
    ushort4 v = *(const ushort4*)&hinb[(size_t)s * HH + colq];
    ax += bf2f(v.x); ay += bf2f(v.y); az += bf2f(v.z); aw += bf2f(v.w);
  }
  ax += __shfl_down(ax, 32);
  ay += __shfl_down(ay, 32);
  az += __shfl_down(az, 32);
  aw += __shfl_down(aw, 32);
  if (half == 0) {
    float inv = d > 0 ? 1.0f / (float)d : 0.0f;
    ushort4 o;
    o.x = f2bf(ax * inv); o.y = f2bf(ay * inv); o.z = f2bf(az * inv); o.w = f2bf(aw * inv);
    *(ushort4*)&aggb[(size_t)wid * HH + colq] = o;
  }
}

// ---- MFMA dual GEMM + bias + BN + ReLU -> bf16 h ----
__global__ __launch_bounds__(256) void k_gemm(const ushortT* __restrict__ aggb, const ushortT* __restrict__ hinb,
                                              const ushortT* __restrict__ wpack, const float* __restrict__ bias,
                                              const float* __restrict__ gma, const float* __restrict__ bta,
                                              const float* __restrict__ mea, const float* __restrict__ var,
                                              ushortT* __restrict__ houtb, int N) {
  __shared__ char Asm[64 * 512];  // 64 rows x 256 bf16, XOR-swizzled
  int tid = threadIdx.x;
  int l = tid & 63;
  int w = tid >> 6;
  int n0 = blockIdx.x * 64;
  int q = l >> 4;
  int ln = l & 15;

  bf16x8 bfr[8][2];
#pragma unroll
  for (int kf = 0; kf < 8; kf++)
#pragma unroll
    for (int nf = 0; nf < 2; nf++) {
      size_t off = (((size_t)kf * 128 + (w * 32 + nf * 16 + ln)) * 4 + q) * 8;
      bfr[kf][nf] = *(const bf16x8*)(wpack + off);
    }

#pragma unroll
  for (int r2 = 0; r2 < 8; r2++) {
    int c = r2 * 256 + tid;
    int row = c >> 5;
    int col16 = c & 31;
    int rg = n0 + row;
    rg = rg < N ? rg : N - 1;
    const ushortT* src = (col16 < 16) ? (aggb + (size_t)rg * HH + col16 * 8)
                                      : (hinb + (size_t)rg * HH + (col16 - 16) * 8);
    float4 v = *(const float4*)src;
    int waddr = row * 512 + ((col16 * 16) ^ ((row & 7) << 4));
    *(float4*)(Asm + waddr) = v;
  }
  __syncthreads();

  f32x4 acc[4][2] = {};
#pragma unroll
  for (int kf = 0; kf < 8; kf++) {
#pragma unroll
    for (int rt = 0; rt < 4; rt++) {
      int row = rt * 16 + ln;
      int raddr = row * 512 + ((kf * 64 + q * 16) ^ ((row & 7) << 4));
      bf16x8 a = *(const bf16x8*)(Asm + raddr);
      acc[rt][0] = __builtin_amdgcn_mfma_f32_16x16x32_bf16(a, bfr[kf][0], acc[rt][0], 0, 0, 0);
      acc[rt][1] = __builtin_amdgcn_mfma_f32_16x16x32_bf16(a, bfr[kf][1], acc[rt][1], 0, 0, 0);
    }
  }

  float sc[2], sh[2];
  int colg[2];
#pragma unroll
  for (int nf = 0; nf < 2; nf++) {
    int c = w * 32 + nf * 16 + ln;
    colg[nf] = c;
    float g = gma[c], vv = var[c], m = mea[c], bt = bta[c], bb = bias[c];
    float s = g * rsqrtf(vv + BN_EPS);
    sc[nf] = s;
    sh[nf] = (bb - m) * s + bt;
  }
#pragma unroll
  for (int rt = 0; rt < 4; rt++)
#pragma unroll
    for (int j = 0; j < 4; j++) {
      int row = n0 + rt * 16 + q * 4 + j;
      if (row < N) {
#pragma unroll
        for (int nf = 0; nf < 2; nf++) {
          float v = fmaxf(acc[rt][nf][j] * sc[nf] + sh[nf], 0.f);
          houtb[(size_t)row * HH + colg[nf]] = f2bf(v);
        }
      }
    }
}

// ---- fused pooling + MLP: one block (128 thr) per graph ----
__global__ __launch_bounds__(128) void k_poolmlp(const ushortT* __restrict__ hb, const int* __restrict__ goff,
                                                 const float* __restrict__ gfeat,
                                                 const float* __restrict__ w1, const float* __restrict__ b1,
                                                 const float* __restrict__ w2, const float* __restrict__ b2,
                                                 float* __restrict__ out) {
  __shared__ float z[HH + GG];
  int g = blockIdx.x;
  int t = threadIdx.x;
  int off = goff[g];
  int cnt = goff[g + 1] - off;
  float s = 0.f;
  int j = 0;
  for (; j + 2 <= cnt; j += 2)
    s += bf2f(hb[(size_t)(off + j) * HH + t]) + bf2f(hb[(size_t)(off + j + 1) * HH + t]);
  if (j < cnt) s += bf2f(hb[(size_t)(off + j) * HH + t]);
  z[t] = s * (cnt > 0 ? 1.0f / (float)cnt : 0.f);
  if (t < GG) z[HH + t] = gfeat[g * GG + t];
  __syncthreads();
  if (t < 64) {
    float acc = b1[t];
#pragma unroll 8
    for (int k = 0; k < HH + GG; k++) acc = fmaf(z[k], w1[k * 64 + t], acc);
    acc = fmaxf(acc, 0.f) * w2[t];
#pragma unroll
    for (int o = 32; o > 0; o >>= 1) acc += __shfl_down(acc, o);
    if (t == 0) out[g] = acc + b2[0];
  }
}

extern "C" void kernel_launch(void* const* d_in, const int* in_sizes, int n_in,
                              void* d_out, int out_size, void* d_ws, size_t ws_size,
                              hipStream_t stream) {
  const float* x = (const float*)d_in[0];
  const int* ei = (const int*)d_in[1];
  const int* batch = (const int*)d_in[2];
  const float* gfeat = (const float*)d_in[3];
  const float* wl = (const float*)d_in[4];
  const float* wr = (const float*)d_in[5];
  const float* bias = (const float*)d_in[6];
  const float* gma = (const float*)d_in[7];
  const float* bta = (const float*)d_in[8];
  const float* mea = (const float*)d_in[9];
  const float* var = (const float*)d_in[10];
  const float* w1 = (const float*)d_in[11];
  const float* b1 = (const float*)d_in[12];
  const float* w2 = (const float*)d_in[13];
  const float* b2 = (const float*)d_in[14];
  int N = in_sizes[0] / HH;
  int E = in_sizes[1] / 2;
  int B = in_sizes[3] / GG;
  float* out = (float*)d_out;
  (void)n_in; (void)out_size; (void)ws_size;

  char* base = (char*)d_ws;
  size_t off = 0;
  auto alloc = [&](size_t bytes) -> void* {
    void* p = base + off;
    off = (off + bytes + 255) & ~(size_t)255;
    return p;
  };
  int* deg = (int*)alloc((size_t)N * 4);
  int* csr_off = (int*)alloc((size_t)N * 4);
  int* goff = (int*)alloc((size_t)(B + 1) * 4);
  uintT* packed = (uintT*)alloc((size_t)E * 4);
  ushortT* rank = (ushortT*)alloc((size_t)E * 2);
  ushortT* csr_us = (ushortT*)alloc((size_t)E * 2);
  ushortT* xb = (ushortT*)alloc((size_t)N * HH * 2);
  ushortT* h1b = (ushortT*)alloc((size_t)N * HH * 2);
  ushortT* h2b = (ushortT*)alloc((size_t)N * HH * 2);
  ushortT* aggb = (ushortT*)alloc((size_t)N * HH * 2);
  ushortT* wpack = (ushortT*)alloc((size_t)LL * 8 * 128 * 4 * 8 * 2);
  int* bsumN = (int*)alloc(1024 * 4);

  hipMemsetAsync(deg, 0, (size_t)N * 4, stream);

  k_degpack<<<(E + 255) / 256, 256, 0, stream>>>(ei, deg, packed, rank, E);
  int total4 = N * HH / 4;
  k_cast<<<(total4 + 255) / 256, 256, 0, stream>>>(x, xb, total4);
  k_gbounds<<<(B + 256) / 256, 256, 0, stream>>>(batch, goff, N, B);

  int nbN = (N + 1023) / 1024;
  k_scan_blk<<<nbN, 1024, 0, stream>>>(deg, csr_off, bsumN, N);
  k_scan_top<<<1, 1024, 0, stream>>>(bsumN, nbN);
  k_scan_add<<<nbN, 1024, 0, stream>>>(csr_off, bsumN, N);

  k_scatter<<<(E + 255) / 256, 256, 0, stream>>>(packed, rank, csr_off, csr_us, E);

  k_prepw<<<(LL * 8 * 128 * 4 + 255) / 256, 256, 0, stream>>>(wl, wr, wpack);

  int nblk = (N + 63) / 64;
  int agg_blk = (N + 3) / 4;  // one wave per node, 4 waves/block
  const ushortT* hsrc[LL] = {xb, h1b, h2b};
  ushortT* hdst[LL] = {h1b, h2b, h1b};
  for (int lyr = 0; lyr < LL; lyr++) {
    k_aggregate<<<agg_blk, 256, 0, stream>>>(csr_off, deg, csr_us, hsrc[lyr], aggb, N);
    k_gemm<<<nblk, 256, 0, stream>>>(aggb, hsrc[lyr], wpack + (size_t)lyr * 32768,
                                     bias + (size_t)lyr * HH, gma + (size_t)lyr * HH, bta + (size_t)lyr * HH,
                                     mea + (size_t)lyr * HH, var + (size_t)lyr * HH, hdst[lyr], N);
  }
  k_poolmlp<<<B, 128, 0, stream>>>(h1b, goff, gfeat, w1, b1, w2, b2, out);
}

// Round 12
// 218.610 us; speedup vs baseline: 1.1422x; 1.0938x over previous
//
#include <hip/hip_runtime.h>

#define HH 128
#define GG 32
#define LL 3
#define BN_EPS 1e-5f

typedef unsigned short ushortT;
typedef unsigned int uintT;
typedef __attribute__((ext_vector_type(8))) short bf16x8;
typedef __attribute__((ext_vector_type(4))) float f32x4;

__device__ inline ushortT f2bf(float f) {
  uintT u = __float_as_uint(f);
  u += 0x7fff + ((u >> 16) & 1);  // RNE
  return (ushortT)(u >> 16);
}
__device__ inline float bf2f(ushortT u) { return __uint_as_float(((uintT)u) << 16); }

// ---- degree count + edge packing + per-edge rank (atomic returns rank within dst list) ----
__global__ __launch_bounds__(256) void k_degpack(const int* __restrict__ ei, int* __restrict__ deg,
                                                 uintT* __restrict__ packed, ushortT* __restrict__ rank, int E) {
  int e = blockIdx.x * 256 + threadIdx.x;
  if (e < E) {
    int d = ei[E + e];
    int s = ei[e];
    int r = atomicAdd(&deg[d], 1);
    packed[e] = ((uintT)d << 16) | (uintT)s;   // plain stores: consumed by k_scatter, keep in L2
    rank[e] = (ushortT)r;
  }
}

// ---- cast fp32 rows -> bf16 mirror ----
__global__ __launch_bounds__(256) void k_cast(const float* __restrict__ in, ushortT* __restrict__ outb, int total4) {
  int i = blockIdx.x * 256 + threadIdx.x;
  if (i < total4) {
    float4 v = *(const float4*)&in[(size_t)i * 4];
    ushort4 o;
    o.x = f2bf(v.x); o.y = f2bf(v.y); o.z = f2bf(v.z); o.w = f2bf(v.w);
    *(ushort4*)&outb[(size_t)i * 4] = o;
  }
}

// ---- graph boundaries via binary search (batch is sorted); goff[B] = N sentinel ----
__global__ __launch_bounds__(256) void k_gbounds(const int* __restrict__ batch, int* __restrict__ goff,
                                                 int N, int B) {
  int g = blockIdx.x * 256 + threadIdx.x;
  if (g > B) return;
  if (g == B) { goff[B] = N; return; }
  int lo = 0, hi = N;
  while (lo < hi) {
    int mid = (lo + hi) >> 1;
    if (batch[mid] < g) lo = mid + 1; else hi = mid;
  }
  goff[g] = lo;
}

// ---- scan: block-local phase ----
__global__ __launch_bounds__(1024) void k_scan_blk(const int* __restrict__ in, int* __restrict__ out,
                                                   int* __restrict__ bsum, int n) {
  __shared__ int sd[1024];
  int tid = threadIdx.x;
  int i = blockIdx.x * 1024 + tid;
  int v = (i < n) ? in[i] : 0;
  sd[tid] = v;
  __syncthreads();
  for (int off = 1; off < 1024; off <<= 1) {
    int t = (tid >= off) ? sd[tid - off] : 0;
    __syncthreads();
    sd[tid] += t;
    __syncthreads();
  }
  if (i < n) out[i] = sd[tid] - v;
  if (tid == 1023) bsum[blockIdx.x] = sd[1023];
}

__global__ __launch_bounds__(1024) void k_scan_top(int* __restrict__ bsum, int nb) {
  __shared__ int sd[1024];
  int tid = threadIdx.x;
  int v = (tid < nb) ? bsum[tid] : 0;
  sd[tid] = v;
  __syncthreads();
  for (int off = 1; off < 1024; off <<= 1) {
    int t = (tid >= off) ? sd[tid - off] : 0;
    __syncthreads();
    sd[tid] += t;
    __syncthreads();
  }
  if (tid < nb) bsum[tid] = sd[tid] - v;
}

__global__ __launch_bounds__(1024) void k_scan_add(int* __restrict__ out0, const int* __restrict__ bsum, int n) {
  int i = blockIdx.x * 1024 + threadIdx.x;
  if (i < n) out0[i] += bsum[blockIdx.x];
}

// ---- atomic-free scatter: pos = csr_off[d] + rank[e] ----
__global__ __launch_bounds__(256) void k_scatter(const uintT* __restrict__ packed, const ushortT* __restrict__ rank,
                                                 const int* __restrict__ csr_off, ushortT* __restrict__ csr_us, int E) {
  int e = blockIdx.x * 256 + threadIdx.x;
  if (e < E) {
    uintT p = packed[e];
    int d = (int)(p >> 16);
    int pos = csr_off[d] + (int)rank[e];
    csr_us[pos] = (ushortT)(p & 0xffffu);   // plain store: csr_us is re-read 3x by aggregates
  }
}

// ---- pack weights for MFMA B-fragment reads ----
__global__ __launch_bounds__(256) void k_prepw(const float* __restrict__ wl, const float* __restrict__ wr,
                                               ushortT* __restrict__ wpack) {
  int idx = blockIdx.x * 256 + threadIdx.x;
  if (idx >= LL * 8 * 128 * 4) return;
  int q = idx & 3;
  int n = (idx >> 2) & 127;
  int kf = (idx >> 9) & 7;
  int layer = idx >> 12;
  ushortT tmp[8];
#pragma unroll
  for (int j = 0; j < 8; j++) {
    int k = kf * 32 + q * 8 + j;
    float w = (k < HH) ? wl[(size_t)layer * HH * HH + k * HH + n]
                       : wr[(size_t)layer * HH * HH + (k - HH) * HH + n];
    tmp[j] = f2bf(w);
  }
  ushort4 a = {tmp[0], tmp[1], tmp[2], tmp[3]};
  ushort4 b = {tmp[4], tmp[5], tmp[6], tmp[7]};
  *(ushort4*)&wpack[(size_t)idx * 8] = a;
  *(ushort4*)&wpack[(size_t)idx * 8 + 4] = b;
}

// ---- mean aggregation: one wave per node, full 256B-row bf16 gather, 16 rows in flight ----
__global__ __launch_bounds__(256) void k_aggregate(const int* __restrict__ csr_off, const int* __restrict__ deg,
                                                   const ushortT* __restrict__ csr_us, const ushortT* __restrict__ hinb,
                                                   ushortT* __restrict__ aggb, int N) {
  int wid = (blockIdx.x * 256 + threadIdx.x) >> 6;
  int lane = threadIdx.x & 63;
  if (wid >= N) return;
  int off = csr_off[wid];
  int d = deg[wid];
  int half = lane >> 5;
  int colq = (lane & 31) * 4;
  float ax = 0.f, ay = 0.f, az = 0.f, aw = 0.f;
  int j = 0;
  for (; j + 16 <= d; j += 16) {  // 16 rows (4KB) in flight
    int s0 = csr_us[off + j + half];
    int s1 = csr_us[off + j + 2 + half];
    int s2 = csr_us[off + j + 4 + half];
    int s3 = csr_us[off + j + 6 + half];
    int s4 = csr_us[off + j + 8 + half];
    int s5 = csr_us[off + j + 10 + half];
    int s6 = csr_us[off + j + 12 + half];
    int s7 = csr_us[off + j + 14 + half];
    ushort4 v0 = *(const ushort4*)&hinb[(size_t)s0 * HH + colq];
    ushort4 v1 = *(const ushort4*)&hinb[(size_t)s1 * HH + colq];
    ushort4 v2 = *(const ushort4*)&hinb[(size_t)s2 * HH + colq];
    ushort4 v3 = *(const ushort4*)&hinb[(size_t)s3 * HH + colq];
    ushort4 v4 = *(const ushort4*)&hinb[(size_t)s4 * HH + colq];
    ushort4 v5 = *(const ushort4*)&hinb[(size_t)s5 * HH + colq];
    ushort4 v6 = *(const ushort4*)&hinb[(size_t)s6 * HH + colq];
    ushort4 v7 = *(const ushort4*)&hinb[(size_t)s7 * HH + colq];
    ax += bf2f(v0.x); ay += bf2f(v0.y); az += bf2f(v0.z); aw += bf2f(v0.w);
    ax += bf2f(v1.x); ay += bf2f(v1.y); az += bf2f(v1.z); aw += bf2f(v1.w);
    ax += bf2f(v2.x); ay += bf2f(v2.y); az += bf2f(v2.z); aw += bf2f(v2.w);
    ax += bf2f(v3.x); ay += bf2f(v3.y); az += bf2f(v3.z); aw += bf2f(v3.w);
    ax += bf2f(v4.x); ay += bf2f(v4.y); az += bf2f(v4.z); aw += bf2f(v4.w);
    ax += bf2f(v5.x); ay += bf2f(v5.y); az += bf2f(v5.z); aw += bf2f(v5.w);
    ax += bf2f(v6.x); ay += bf2f(v6.y); az += bf2f(v6.z); aw += bf2f(v6.w);
    ax += bf2f(v7.x); ay += bf2f(v7.y); az += bf2f(v7.z); aw += bf2f(v7.w);
  }
  for (; j + 8 <= d; j += 8) {  // 8 rows (2KB) in flight
    int s0 = csr_us[off + j + half];
    int s1 = csr_us[off + j + 2 + half];
    int s2 = csr_us[off + j + 4 + half];
    int s3 = csr_us[off + j + 6 + half];
    ushort4 v0 = *(const ushort4*)&hinb[(size_t)s0 * HH + colq];
    ushort4 v1 = *(const ushort4*)&hinb[(size_t)s1 * HH + colq];
    ushort4 v2 = *(const ushort4*)&hinb[(size_t)s2 * HH + colq];
    ushort4 v3 = *(const ushort4*)&hinb[(size_t)s3 * HH + colq];
    ax += bf2f(v0.x); ay += bf2f(v0.y); az += bf2f(v0.z); aw += bf2f(v0.w);
    ax += bf2f(v1.x); ay += bf2f(v1.y); az += bf2f(v1.z); aw += bf2f(v1.w);
    ax += bf2f(v2.x); ay += bf2f(v2.y); az += bf2f(v2.z); aw += bf2f(v2.w);
    ax += bf2f(v3.x); ay += bf2f(v3.y); az += bf2f(v3.z); aw += bf2f(v3.w);
  }
  for (; j + 2 <= d; j += 2) {
    int s = csr_us[off + j + half];
    ushort4 v = *(const ushort4*)&hinb[(size_t)s * HH + colq];
    ax += bf2f(v.x); ay += bf2f(v.y); az += bf2f(v.z); aw += bf2f(v.w);
  }
  if (j < d && half == 0) {
    int s = csr_us[off + j];
    ushort4 v = *(const ushort4*)&hinb[(size_t)s * HH + colq];
    ax += bf2f(v.x); ay += bf2f(v.y); az += bf2f(v.z); aw += bf2f(v.w);
  }
  ax += __shfl_down(ax, 32);
  ay += __shfl_down(ay, 32);
  az += __shfl_down(az, 32);
  aw += __shfl_down(aw, 32);
  if (half == 0) {
    float inv = d > 0 ? 1.0f / (float)d : 0.0f;
    ushort4 o;
    o.x = f2bf(ax * inv); o.y = f2bf(ay * inv); o.z = f2bf(az * inv); o.w = f2bf(aw * inv);
    *(ushort4*)&aggb[(size_t)wid * HH + colq] = o;
  }
}

// ---- MFMA dual GEMM + bias + BN + ReLU -> bf16 h ----
__global__ __launch_bounds__(256) void k_gemm(const ushortT* __restrict__ aggb, const ushortT* __restrict__ hinb,
                                              const ushortT* __restrict__ wpack, const float* __restrict__ bias,
                                              const float* __restrict__ gma, const float* __restrict__ bta,
                                              const float* __restrict__ mea, const float* __restrict__ var,
                                              ushortT* __restrict__ houtb, int N) {
  __shared__ char Asm[64 * 512];  // 64 rows x 256 bf16, XOR-swizzled
  int tid = threadIdx.x;
  int l = tid & 63;
  int w = tid >> 6;
  int n0 = blockIdx.x * 64;
  int q = l >> 4;
  int ln = l & 15;

  bf16x8 bfr[8][2];
#pragma unroll
  for (int kf = 0; kf < 8; kf++)
#pragma unroll
    for (int nf = 0; nf < 2; nf++) {
      size_t off = (((size_t)kf * 128 + (w * 32 + nf * 16 + ln)) * 4 + q) * 8;
      bfr[kf][nf] = *(const bf16x8*)(wpack + off);
    }

#pragma unroll
  for (int r2 = 0; r2 < 8; r2++) {
    int c = r2 * 256 + tid;
    int row = c >> 5;
    int col16 = c & 31;
    int rg = n0 + row;
    rg = rg < N ? rg : N - 1;
    const ushortT* src = (col16 < 16) ? (aggb + (size_t)rg * HH + col16 * 8)
                                      : (hinb + (size_t)rg * HH + (col16 - 16) * 8);
    float4 v = *(const float4*)src;
    int waddr = row * 512 + ((col16 * 16) ^ ((row & 7) << 4));
    *(float4*)(Asm + waddr) = v;
  }
  __syncthreads();

  f32x4 acc[4][2] = {};
#pragma unroll
  for (int kf = 0; kf < 8; kf++) {
#pragma unroll
    for (int rt = 0; rt < 4; rt++) {
      int row = rt * 16 + ln;
      int raddr = row * 512 + ((kf * 64 + q * 16) ^ ((row & 7) << 4));
      bf16x8 a = *(const bf16x8*)(Asm + raddr);
      acc[rt][0] = __builtin_amdgcn_mfma_f32_16x16x32_bf16(a, bfr[kf][0], acc[rt][0], 0, 0, 0);
      acc[rt][1] = __builtin_amdgcn_mfma_f32_16x16x32_bf16(a, bfr[kf][1], acc[rt][1], 0, 0, 0);
    }
  }

  float sc[2], sh[2];
  int colg[2];
#pragma unroll
  for (int nf = 0; nf < 2; nf++) {
    int c = w * 32 + nf * 16 + ln;
    colg[nf] = c;
    float g = gma[c], vv = var[c], m = mea[c], bt = bta[c], bb = bias[c];
    float s = g * rsqrtf(vv + BN_EPS);
    sc[nf] = s;
    sh[nf] = (bb - m) * s + bt;
  }
#pragma unroll
  for (int rt = 0; rt < 4; rt++)
#pragma unroll
    for (int j = 0; j < 4; j++) {
      int row = n0 + rt * 16 + q * 4 + j;
      if (row < N) {
#pragma unroll
        for (int nf = 0; nf < 2; nf++) {
          float v = fmaxf(acc[rt][nf][j] * sc[nf] + sh[nf], 0.f);
          houtb[(size_t)row * HH + colg[nf]] = f2bf(v);
        }
      }
    }
}

// ---- fused pooling + MLP: one block (128 thr) per graph ----
__global__ __launch_bounds__(128) void k_poolmlp(const ushortT* __restrict__ hb, const int* __restrict__ goff,
                                                 const float* __restrict__ gfeat,
                                                 const float* __restrict__ w1, const float* __restrict__ b1,
                                                 const float* __restrict__ w2, const float* __restrict__ b2,
                                                 float* __restrict__ out) {
  __shared__ float z[HH + GG];
  int g = blockIdx.x;
  int t = threadIdx.x;
  int off = goff[g];
  int cnt = goff[g + 1] - off;
  float s = 0.f;
  int j = 0;
  for (; j + 2 <= cnt; j += 2)
    s += bf2f(hb[(size_t)(off + j) * HH + t]) + bf2f(hb[(size_t)(off + j + 1) * HH + t]);
  if (j < cnt) s += bf2f(hb[(size_t)(off + j) * HH + t]);
  z[t] = s * (cnt > 0 ? 1.0f / (float)cnt : 0.f);
  if (t < GG) z[HH + t] = gfeat[g * GG + t];
  __syncthreads();
  if (t < 64) {
    float acc = b1[t];
#pragma unroll 8
    for (int k = 0; k < HH + GG; k++) acc = fmaf(z[k], w1[k * 64 + t], acc);
    acc = fmaxf(acc, 0.f) * w2[t];
#pragma unroll
    for (int o = 32; o > 0; o >>= 1) acc += __shfl_down(acc, o);
    if (t == 0) out[g] = acc + b2[0];
  }
}

extern "C" void kernel_launch(void* const* d_in, const int* in_sizes, int n_in,
                              void* d_out, int out_size, void* d_ws, size_t ws_size,
                              hipStream_t stream) {
  const float* x = (const float*)d_in[0];
  const int* ei = (const int*)d_in[1];
  const int* batch = (const int*)d_in[2];
  const float* gfeat = (const float*)d_in[3];
  const float* wl = (const float*)d_in[4];
  const float* wr = (const float*)d_in[5];
  const float* bias = (const float*)d_in[6];
  const float* gma = (const float*)d_in[7];
  const float* bta = (const float*)d_in[8];
  const float* mea = (const float*)d_in[9];
  const float* var = (const float*)d_in[10];
  const float* w1 = (const float*)d_in[11];
  const float* b1 = (const float*)d_in[12];
  const float* w2 = (const float*)d_in[13];
  const float* b2 = (const float*)d_in[14];
  int N = in_sizes[0] / HH;
  int E = in_sizes[1] / 2;
  int B = in_sizes[3] / GG;
  float* out = (float*)d_out;
  (void)n_in; (void)out_size; (void)ws_size;

  char* base = (char*)d_ws;
  size_t off = 0;
  auto alloc = [&](size_t bytes) -> void* {
    void* p = base + off;
    off = (off + bytes + 255) & ~(size_t)255;
    return p;
  };
  int* deg = (int*)alloc((size_t)N * 4);
  int* csr_off = (int*)alloc((size_t)N * 4);
  int* goff = (int*)alloc((size_t)(B + 1) * 4);
  uintT* packed = (uintT*)alloc((size_t)E * 4);
  ushortT* rank = (ushortT*)alloc((size_t)E * 2);
  ushortT* csr_us = (ushortT*)alloc((size_t)E * 2);
  ushortT* xb = (ushortT*)alloc((size_t)N * HH * 2);
  ushortT* h1b = (ushortT*)alloc((size_t)N * HH * 2);
  ushortT* h2b = (ushortT*)alloc((size_t)N * HH * 2);
  ushortT* aggb = (ushortT*)alloc((size_t)N * HH * 2);
  ushortT* wpack = (ushortT*)alloc((size_t)LL * 8 * 128 * 4 * 8 * 2);
  int* bsumN = (int*)alloc(1024 * 4);

  hipMemsetAsync(deg, 0, (size_t)N * 4, stream);

  k_degpack<<<(E + 255) / 256, 256, 0, stream>>>(ei, deg, packed, rank, E);
  int total4 = N * HH / 4;
  k_cast<<<(total4 + 255) / 256, 256, 0, stream>>>(x, xb, total4);
  k_gbounds<<<(B + 256) / 256, 256, 0, stream>>>(batch, goff, N, B);

  int nbN = (N + 1023) / 1024;
  k_scan_blk<<<nbN, 1024, 0, stream>>>(deg, csr_off, bsumN, N);
  k_scan_top<<<1, 1024, 0, stream>>>(bsumN, nbN);
  k_scan_add<<<nbN, 1024, 0, stream>>>(csr_off, bsumN, N);

  k_scatter<<<(E + 255) / 256, 256, 0, stream>>>(packed, rank, csr_off, csr_us, E);

  k_prepw<<<(LL * 8 * 128 * 4 + 255) / 256, 256, 0, stream>>>(wl, wr, wpack);

  int nblk = (N + 63) / 64;
  int agg_blk = (N + 3) / 4;  // one wave per node, 4 waves/block
  const ushortT* hsrc[LL] = {xb, h1b, h2b};
  ushortT* hdst[LL] = {h1b, h2b, h1b};
  for (int lyr = 0; lyr < LL; lyr++) {
    k_aggregate<<<agg_blk, 256, 0, stream>>>(csr_off, deg, csr_us, hsrc[lyr], aggb, N);
    k_gemm<<<nblk, 256, 0, stream>>>(aggb, hsrc[lyr], wpack + (size_t)lyr * 32768,
                                     bias + (size_t)lyr * HH, gma + (size_t)lyr * HH, bta + (size_t)lyr * HH,
                                     mea + (size_t)lyr * HH, var + (size_t)lyr * HH, hdst[lyr], N);
  }
  k_poolmlp<<<B, 128, 0, stream>>>(h1b, goff, gfeat, w1, b1, w2, b2, out);
}

// Round 13
// 214.468 us; speedup vs baseline: 1.1642x; 1.0193x over previous
//
#include <hip/hip_runtime.h>

#define HH 128
#define GG 32
#define LL 3
#define BN_EPS 1e-5f

typedef unsigned short ushortT;
typedef unsigned int uintT;
typedef __attribute__((ext_vector_type(8))) short bf16x8;
typedef __attribute__((ext_vector_type(8))) unsigned short us8;
typedef __attribute__((ext_vector_type(4))) float f32x4;

__device__ inline ushortT f2bf(float f) {
  uintT u = __float_as_uint(f);
  u += 0x7fff + ((u >> 16) & 1);  // RNE
  return (ushortT)(u >> 16);
}
__device__ inline float bf2f(ushortT u) { return __uint_as_float(((uintT)u) << 16); }

// ---- degree count + edge packing + per-edge rank (atomic returns rank within dst list) ----
__global__ __launch_bounds__(256) void k_degpack(const int* __restrict__ ei, int* __restrict__ deg,
                                                 uintT* __restrict__ packed, ushortT* __restrict__ rank, int E) {
  int e = blockIdx.x * 256 + threadIdx.x;
  if (e < E) {
    int d = ei[E + e];
    int s = ei[e];
    int r = atomicAdd(&deg[d], 1);
    packed[e] = ((uintT)d << 16) | (uintT)s;
    rank[e] = (ushortT)r;
  }
}

// ---- fused prep: x->bf16 cast | graph bounds (binary search) | weight pack ----
__global__ __launch_bounds__(256) void k_prep2(const float* __restrict__ x, ushortT* __restrict__ xb, int total4,
                                               const int* __restrict__ batch, int* __restrict__ goff, int N, int B,
                                               const float* __restrict__ wl, const float* __restrict__ wr,
                                               ushortT* __restrict__ wpack) {
  int i = blockIdx.x * 256 + threadIdx.x;
  if (i < total4) {
    float4 v = *(const float4*)&x[(size_t)i * 4];
    ushort4 o;
    o.x = f2bf(v.x); o.y = f2bf(v.y); o.z = f2bf(v.z); o.w = f2bf(v.w);
    *(ushort4*)&xb[(size_t)i * 4] = o;
  }
  if (i <= B) {
    if (i == B) goff[B] = N;
    else {
      int lo = 0, hi = N;
      while (lo < hi) {
        int mid = (lo + hi) >> 1;
        if (batch[mid] < i) lo = mid + 1; else hi = mid;
      }
      goff[i] = lo;
    }
  }
  if (i < LL * 8 * 128 * 4) {
    int q = i & 3;
    int n = (i >> 2) & 127;
    int kf = (i >> 9) & 7;
    int layer = i >> 12;
    ushortT tmp[8];
#pragma unroll
    for (int j = 0; j < 8; j++) {
      int k = kf * 32 + q * 8 + j;
      float w = (k < HH) ? wl[(size_t)layer * HH * HH + k * HH + n]
                         : wr[(size_t)layer * HH * HH + (k - HH) * HH + n];
      tmp[j] = f2bf(w);
    }
    ushort4 a = {tmp[0], tmp[1], tmp[2], tmp[3]};
    ushort4 b = {tmp[4], tmp[5], tmp[6], tmp[7]};
    *(ushort4*)&wpack[(size_t)i * 8] = a;
    *(ushort4*)&wpack[(size_t)i * 8 + 4] = b;
  }
}

// ---- scan: block-local phase ----
__global__ __launch_bounds__(1024) void k_scan_blk(const int* __restrict__ in, int* __restrict__ out,
                                                   int* __restrict__ bsum, int n) {
  __shared__ int sd[1024];
  int tid = threadIdx.x;
  int i = blockIdx.x * 1024 + tid;
  int v = (i < n) ? in[i] : 0;
  sd[tid] = v;
  __syncthreads();
  for (int off = 1; off < 1024; off <<= 1) {
    int t = (tid >= off) ? sd[tid - off] : 0;
    __syncthreads();
    sd[tid] += t;
    __syncthreads();
  }
  if (i < n) out[i] = sd[tid] - v;
  if (tid == 1023) bsum[blockIdx.x] = sd[1023];
}

__global__ __launch_bounds__(1024) void k_scan_top(int* __restrict__ bsum, int nb) {
  __shared__ int sd[1024];
  int tid = threadIdx.x;
  int v = (tid < nb) ? bsum[tid] : 0;
  sd[tid] = v;
  __syncthreads();
  for (int off = 1; off < 1024; off <<= 1) {
    int t = (tid >= off) ? sd[tid - off] : 0;
    __syncthreads();
    sd[tid] += t;
    __syncthreads();
  }
  if (tid < nb) bsum[tid] = sd[tid] - v;
}

__global__ __launch_bounds__(1024) void k_scan_add(int* __restrict__ out0, const int* __restrict__ bsum, int n) {
  int i = blockIdx.x * 1024 + threadIdx.x;
  if (i < n) out0[i] += bsum[blockIdx.x];
}

// ---- atomic-free scatter: pos = csr_off[d] + rank[e] ----
__global__ __launch_bounds__(256) void k_scatter(const uintT* __restrict__ packed, const ushortT* __restrict__ rank,
                                                 const int* __restrict__ csr_off, ushortT* __restrict__ csr_us, int E) {
  int e = blockIdx.x * 256 + threadIdx.x;
  if (e < E) {
    uintT p = packed[e];
    int d = (int)(p >> 16);
    int pos = csr_off[d] + (int)rank[e];
    csr_us[pos] = (ushortT)(p & 0xffffu);
  }
}

// ---- mean aggregation: one wave per node, 4 row-slots x 16 col-lanes, 16B loads ----
// lane = qrt*16 + li: row slot qrt handles rows {j : j%4==qrt}, li covers cols li*8..li*8+7
// #pragma unroll 4 -> 4 independent 16B loads/lane in flight = 16 rows (4KB) per wave
__global__ __launch_bounds__(256) void k_aggregate(const int* __restrict__ csr_off, const int* __restrict__ deg,
                                                   const ushortT* __restrict__ csr_us, const ushortT* __restrict__ hinb,
                                                   ushortT* __restrict__ aggb, int N) {
  int wid = (blockIdx.x * 256 + threadIdx.x) >> 6;
  int lane = threadIdx.x & 63;
  if (wid >= N) return;
  int off = csr_off[wid];
  int d = deg[wid];
  int qrt = lane >> 4;
  int li = lane & 15;
  float acc[8] = {};
#pragma unroll 4
  for (int j = qrt; j < d; j += 4) {
    int s = csr_us[off + j];
    us8 v = *(const us8*)&hinb[(size_t)s * HH + li * 8];
#pragma unroll
    for (int k = 0; k < 8; k++) acc[k] += bf2f(v[k]);
  }
#pragma unroll
  for (int k = 0; k < 8; k++) {
    acc[k] += __shfl_xor(acc[k], 16);
    acc[k] += __shfl_xor(acc[k], 32);
  }
  if (lane < 16) {
    float inv = d > 0 ? 1.0f / (float)d : 0.0f;
    uint4 o;
    o.x = (uintT)f2bf(acc[0] * inv) | ((uintT)f2bf(acc[1] * inv) << 16);
    o.y = (uintT)f2bf(acc[2] * inv) | ((uintT)f2bf(acc[3] * inv) << 16);
    o.z = (uintT)f2bf(acc[4] * inv) | ((uintT)f2bf(acc[5] * inv) << 16);
    o.w = (uintT)f2bf(acc[6] * inv) | ((uintT)f2bf(acc[7] * inv) << 16);
    *(uint4*)&aggb[(size_t)wid * HH + li * 8] = o;
  }
}

// ---- MFMA dual GEMM + bias + BN + ReLU -> bf16 h ----
__global__ __launch_bounds__(256) void k_gemm(const ushortT* __restrict__ aggb, const ushortT* __restrict__ hinb,
                                              const ushortT* __restrict__ wpack, const float* __restrict__ bias,
                                              const float* __restrict__ gma, const float* __restrict__ bta,
                                              const float* __restrict__ mea, const float* __restrict__ var,
                                              ushortT* __restrict__ houtb, int N) {
  __shared__ char Asm[64 * 512];  // 64 rows x 256 bf16, XOR-swizzled
  int tid = threadIdx.x;
  int l = tid & 63;
  int w = tid >> 6;
  int n0 = blockIdx.x * 64;
  int q = l >> 4;
  int ln = l & 15;

  bf16x8 bfr[8][2];
#pragma unroll
  for (int kf = 0; kf < 8; kf++)
#pragma unroll
    for (int nf = 0; nf < 2; nf++) {
      size_t off = (((size_t)kf * 128 + (w * 32 + nf * 16 + ln)) * 4 + q) * 8;
      bfr[kf][nf] = *(const bf16x8*)(wpack + off);
    }

#pragma unroll
  for (int r2 = 0; r2 < 8; r2++) {
    int c = r2 * 256 + tid;
    int row = c >> 5;
    int col16 = c & 31;
    int rg = n0 + row;
    rg = rg < N ? rg : N - 1;
    const ushortT* src = (col16 < 16) ? (aggb + (size_t)rg * HH + col16 * 8)
                                      : (hinb + (size_t)rg * HH + (col16 - 16) * 8);
    float4 v = *(const float4*)src;
    int waddr = row * 512 + ((col16 * 16) ^ ((row & 7) << 4));
    *(float4*)(Asm + waddr) = v;
  }
  __syncthreads();

  f32x4 acc[4][2] = {};
#pragma unroll
  for (int kf = 0; kf < 8; kf++) {
#pragma unroll
    for (int rt = 0; rt < 4; rt++) {
      int row = rt * 16 + ln;
      int raddr = row * 512 + ((kf * 64 + q * 16) ^ ((row & 7) << 4));
      bf16x8 a = *(const bf16x8*)(Asm + raddr);
      acc[rt][0] = __builtin_amdgcn_mfma_f32_16x16x32_bf16(a, bfr[kf][0], acc[rt][0], 0, 0, 0);
      acc[rt][1] = __builtin_amdgcn_mfma_f32_16x16x32_bf16(a, bfr[kf][1], acc[rt][1], 0, 0, 0);
    }
  }

  float sc[2], sh[2];
  int colg[2];
#pragma unroll
  for (int nf = 0; nf < 2; nf++) {
    int c = w * 32 + nf * 16 + ln;
    colg[nf] = c;
    float g = gma[c], vv = var[c], m = mea[c], bt = bta[c], bb = bias[c];
    float s = g * rsqrtf(vv + BN_EPS);
    sc[nf] = s;
    sh[nf] = (bb - m) * s + bt;
  }
#pragma unroll
  for (int rt = 0; rt < 4; rt++)
#pragma unroll
    for (int j = 0; j < 4; j++) {
      int row = n0 + rt * 16 + q * 4 + j;
      if (row < N) {
#pragma unroll
        for (int nf = 0; nf < 2; nf++) {
          float v = fmaxf(acc[rt][nf][j] * sc[nf] + sh[nf], 0.f);
          houtb[(size_t)row * HH + colg[nf]] = f2bf(v);
        }
      }
    }
}

// ---- fused pooling + MLP: one block (128 thr) per graph ----
__global__ __launch_bounds__(128) void k_poolmlp(const ushortT* __restrict__ hb, const int* __restrict__ goff,
                                                 const float* __restrict__ gfeat,
                                                 const float* __restrict__ w1, const float* __restrict__ b1,
                                                 const float* __restrict__ w2, const float* __restrict__ b2,
                                                 float* __restrict__ out) {
  __shared__ float z[HH + GG];
  int g = blockIdx.x;
  int t = threadIdx.x;
  int off = goff[g];
  int cnt = goff[g + 1] - off;
  float s = 0.f;
  int j = 0;
  for (; j + 2 <= cnt; j += 2)
    s += bf2f(hb[(size_t)(off + j) * HH + t]) + bf2f(hb[(size_t)(off + j + 1) * HH + t]);
  if (j < cnt) s += bf2f(hb[(size_t)(off + j) * HH + t]);
  z[t] = s * (cnt > 0 ? 1.0f / (float)cnt : 0.f);
  if (t < GG) z[HH + t] = gfeat[g * GG + t];
  __syncthreads();
  if (t < 64) {
    float acc = b1[t];
#pragma unroll 8
    for (int k = 0; k < HH + GG; k++) acc = fmaf(z[k], w1[k * 64 + t], acc);
    acc = fmaxf(acc, 0.f) * w2[t];
#pragma unroll
    for (int o = 32; o > 0; o >>= 1) acc += __shfl_down(acc, o);
    if (t == 0) out[g] = acc + b2[0];
  }
}

extern "C" void kernel_launch(void* const* d_in, const int* in_sizes, int n_in,
                              void* d_out, int out_size, void* d_ws, size_t ws_size,
                              hipStream_t stream) {
  const float* x = (const float*)d_in[0];
  const int* ei = (const int*)d_in[1];
  const int* batch = (const int*)d_in[2];
  const float* gfeat = (const float*)d_in[3];
  const float* wl = (const float*)d_in[4];
  const float* wr = (const float*)d_in[5];
  const float* bias = (const float*)d_in[6];
  const float* gma = (const float*)d_in[7];
  const float* bta = (const float*)d_in[8];
  const float* mea = (const float*)d_in[9];
  const float* var = (const float*)d_in[10];
  const float* w1 = (const float*)d_in[11];
  const float* b1 = (const float*)d_in[12];
  const float* w2 = (const float*)d_in[13];
  const float* b2 = (const float*)d_in[14];
  int N = in_sizes[0] / HH;
  int E = in_sizes[1] / 2;
  int B = in_sizes[3] / GG;
  float* out = (float*)d_out;
  (void)n_in; (void)out_size; (void)ws_size;

  char* base = (char*)d_ws;
  size_t off = 0;
  auto alloc = [&](size_t bytes) -> void* {
    void* p = base + off;
    off = (off + bytes + 255) & ~(size_t)255;
    return p;
  };
  int* deg = (int*)alloc((size_t)N * 4);
  int* csr_off = (int*)alloc((size_t)N * 4);
  int* goff = (int*)alloc((size_t)(B + 1) * 4);
  uintT* packed = (uintT*)alloc((size_t)E * 4);
  ushortT* rank = (ushortT*)alloc((size_t)E * 2);
  ushortT* csr_us = (ushortT*)alloc((size_t)E * 2);
  ushortT* xb = (ushortT*)alloc((size_t)N * HH * 2);
  ushortT* h1b = (ushortT*)alloc((size_t)N * HH * 2);
  ushortT* h2b = (ushortT*)alloc((size_t)N * HH * 2);
  ushortT* aggb = (ushortT*)alloc((size_t)N * HH * 2);
  ushortT* wpack = (ushortT*)alloc((size_t)LL * 8 * 128 * 4 * 8 * 2);
  int* bsumN = (int*)alloc(1024 * 4);

  hipMemsetAsync(deg, 0, (size_t)N * 4, stream);

  k_degpack<<<(E + 255) / 256, 256, 0, stream>>>(ei, deg, packed, rank, E);

  int total4 = N * HH / 4;
  k_prep2<<<(total4 + 255) / 256, 256, 0, stream>>>(x, xb, total4, batch, goff, N, B, wl, wr, wpack);

  int nbN = (N + 1023) / 1024;
  k_scan_blk<<<nbN, 1024, 0, stream>>>(deg, csr_off, bsumN, N);
  k_scan_top<<<1, 1024, 0, stream>>>(bsumN, nbN);
  k_scan_add<<<nbN, 1024, 0, stream>>>(csr_off, bsumN, N);

  k_scatter<<<(E + 255) / 256, 256, 0, stream>>>(packed, rank, csr_off, csr_us, E);

  int nblk = (N + 63) / 64;
  int agg_blk = (N + 3) / 4;  // one wave per node, 4 waves/block
  const ushortT* hsrc[LL] = {xb, h1b, h2b};
  ushortT* hdst[LL] = {h1b, h2b, h1b};
  for (int lyr = 0; lyr < LL; lyr++) {
    k_aggregate<<<agg_blk, 256, 0, stream>>>(csr_off, deg, csr_us, hsrc[lyr], aggb, N);
    k_gemm<<<nblk, 256, 0, stream>>>(aggb, hsrc[lyr], wpack + (size_t)lyr * 32768,
                                     bias + (size_t)lyr * HH, gma + (size_t)lyr * HH, bta + (size_t)lyr * HH,
                                     mea + (size_t)lyr * HH, var + (size_t)lyr * HH, hdst[lyr], N);
  }
  k_poolmlp<<<B, 128, 0, stream>>>(h1b, goff, gfeat, w1, b1, w2, b2, out);
}